// Round 1
// baseline (677.238 us; speedup 1.0000x reference)
//
#include <hip/hip_runtime.h>

// Problem constants (fixed by the reference)
#define NE 32      // experts
#define NT 2048    // tokens
#define NH 1024    // hidden
#define NI 512     // intermediate
#define NK 4       // top-k
#define CAP 512    // max routed entries per expert (mean=256, 16 sigma margin)
#define TM 64      // entry-tile
#define TN 64      // output-tile
#define KB 32      // k-chunk
#define PAD 68     // padded row stride for transposed LDS tiles (68*4=272B, 16B-aligned)

// ---------------- routing: build per-expert (token*K+k, weight) lists ----------------
__global__ void route_kernel(const int* __restrict__ idx,
                             const float* __restrict__ w,
                             int* __restrict__ counts,
                             int* __restrict__ tok,
                             float* __restrict__ wgt) {
    int tid = blockIdx.x * blockDim.x + threadIdx.x;
    if (tid >= NT * NK) return;
    int e = idx[tid];
    int pos = atomicAdd(&counts[e], 1);
    if (pos < CAP) {
        tok[e * CAP + pos] = tid;          // tid = t*NK + k
        wgt[e * CAP + pos] = w[tid];
    }
}

// ---------------- gate/up GEMM + SiLU: h[(t*K+k), :NI] ----------------
// tile: TM entries x TN j-outputs (gate and up), K-loop over NH in KB chunks
__global__ __launch_bounds__(256) void gateup_kernel(
    const float* __restrict__ hidden,
    const float* __restrict__ gup,     // [NE][2*NI][NH]
    const int* __restrict__ counts,
    const int* __restrict__ tok,
    float* __restrict__ hbuf)          // [NT*NK][NI]
{
    int e = blockIdx.z;
    int cnt = counts[e];
    int m0 = blockIdx.y * TM;
    if (m0 >= cnt) return;
    int j0 = blockIdx.x * TN;

    __shared__ __align__(16) float Xs[KB][PAD];
    __shared__ __align__(16) float Wg[KB][PAD];
    __shared__ __align__(16) float Wu[KB][PAD];
    __shared__ int tks[TM];

    int tid = threadIdx.x;
    if (tid < TM) {
        int mi = m0 + tid;
        tks[tid] = tok[e * CAP + (mi < cnt ? mi : m0)];
    }
    __syncthreads();

    int tx = tid & 15;   // n-quad (j = j0 + tx*4 + b)
    int ty = tid >> 4;   // m-quad (m = ty*4 + a)
    const float* gup_e = gup + (size_t)e * (2 * NI) * NH;

    float accg[4][4], accu[4][4];
#pragma unroll
    for (int a = 0; a < 4; a++)
#pragma unroll
        for (int b = 0; b < 4; b++) { accg[a][b] = 0.f; accu[a][b] = 0.f; }

    for (int h0 = 0; h0 < NH; h0 += KB) {
        // stage: 512 float4-quads per array, 2 per thread per array, transposed into LDS
#pragma unroll
        for (int q = 0; q < 2; q++) {
            int Q = tid * 2 + q;
            int m = Q >> 3, kq = Q & 7;
            int t = tks[m] >> 2;
            float4 xv = *(const float4*)(hidden + (size_t)t * NH + h0 + kq * 4);
            Xs[kq * 4 + 0][m] = xv.x; Xs[kq * 4 + 1][m] = xv.y;
            Xs[kq * 4 + 2][m] = xv.z; Xs[kq * 4 + 3][m] = xv.w;
            int n = m;
            float4 gv = *(const float4*)(gup_e + (size_t)(j0 + n) * NH + h0 + kq * 4);
            Wg[kq * 4 + 0][n] = gv.x; Wg[kq * 4 + 1][n] = gv.y;
            Wg[kq * 4 + 2][n] = gv.z; Wg[kq * 4 + 3][n] = gv.w;
            float4 uv = *(const float4*)(gup_e + (size_t)(NI + j0 + n) * NH + h0 + kq * 4);
            Wu[kq * 4 + 0][n] = uv.x; Wu[kq * 4 + 1][n] = uv.y;
            Wu[kq * 4 + 2][n] = uv.z; Wu[kq * 4 + 3][n] = uv.w;
        }
        __syncthreads();
#pragma unroll
        for (int kk = 0; kk < KB; kk++) {
            float4 xv = *(const float4*)&Xs[kk][ty * 4];
            float4 gv = *(const float4*)&Wg[kk][tx * 4];
            float4 uv = *(const float4*)&Wu[kk][tx * 4];
            float xa[4] = {xv.x, xv.y, xv.z, xv.w};
            float ga[4] = {gv.x, gv.y, gv.z, gv.w};
            float ua[4] = {uv.x, uv.y, uv.z, uv.w};
#pragma unroll
            for (int a = 0; a < 4; a++)
#pragma unroll
                for (int b = 0; b < 4; b++) {
                    accg[a][b] += xa[a] * ga[b];
                    accu[a][b] += xa[a] * ua[b];
                }
        }
        __syncthreads();
    }

#pragma unroll
    for (int a = 0; a < 4; a++) {
        int m = ty * 4 + a;
        if (m0 + m < cnt) {
            int tk = tks[m];
            float r[4];
#pragma unroll
            for (int b = 0; b < 4; b++) {
                float g = accg[a][b];
                float s = g / (1.f + __expf(-g));   // silu
                r[b] = s * accu[a][b];
            }
            *(float4*)(hbuf + (size_t)tk * NI + j0 + tx * 4) =
                make_float4(r[0], r[1], r[2], r[3]);
        }
    }
}

// ---------------- down GEMM + weight-scale + atomic accumulate ----------------
__global__ __launch_bounds__(256) void down_kernel(
    const float* __restrict__ hbuf,    // [NT*NK][NI]
    const float* __restrict__ down,    // [NE][NH][NI]
    const int* __restrict__ counts,
    const int* __restrict__ tok,
    const float* __restrict__ wgt,
    float* __restrict__ out)           // [NT][NH]
{
    int e = blockIdx.z;
    int cnt = counts[e];
    int m0 = blockIdx.y * TM;
    if (m0 >= cnt) return;
    int n0 = blockIdx.x * TN;   // over NH

    __shared__ __align__(16) float Xs[KB][PAD];
    __shared__ __align__(16) float Ws[KB][PAD];
    __shared__ int tks[TM];
    __shared__ float wls[TM];

    int tid = threadIdx.x;
    if (tid < TM) {
        int mi = m0 + tid;
        int src = e * CAP + (mi < cnt ? mi : m0);
        tks[tid] = tok[src];
        wls[tid] = wgt[src];
    }
    __syncthreads();

    int tx = tid & 15;
    int ty = tid >> 4;
    const float* down_e = down + (size_t)e * NH * NI;

    float acc[4][4];
#pragma unroll
    for (int a = 0; a < 4; a++)
#pragma unroll
        for (int b = 0; b < 4; b++) acc[a][b] = 0.f;

    for (int i0 = 0; i0 < NI; i0 += KB) {
#pragma unroll
        for (int q = 0; q < 2; q++) {
            int Q = tid * 2 + q;
            int m = Q >> 3, kq = Q & 7;
            int tk = tks[m];
            float4 xv = *(const float4*)(hbuf + (size_t)tk * NI + i0 + kq * 4);
            Xs[kq * 4 + 0][m] = xv.x; Xs[kq * 4 + 1][m] = xv.y;
            Xs[kq * 4 + 2][m] = xv.z; Xs[kq * 4 + 3][m] = xv.w;
            int n = m;
            float4 wv = *(const float4*)(down_e + (size_t)(n0 + n) * NI + i0 + kq * 4);
            Ws[kq * 4 + 0][n] = wv.x; Ws[kq * 4 + 1][n] = wv.y;
            Ws[kq * 4 + 2][n] = wv.z; Ws[kq * 4 + 3][n] = wv.w;
        }
        __syncthreads();
#pragma unroll
        for (int kk = 0; kk < KB; kk++) {
            float4 xv = *(const float4*)&Xs[kk][ty * 4];
            float4 wv = *(const float4*)&Ws[kk][tx * 4];
            float xa[4] = {xv.x, xv.y, xv.z, xv.w};
            float wa[4] = {wv.x, wv.y, wv.z, wv.w};
#pragma unroll
            for (int a = 0; a < 4; a++)
#pragma unroll
                for (int b = 0; b < 4; b++) acc[a][b] += xa[a] * wa[b];
        }
        __syncthreads();
    }

#pragma unroll
    for (int a = 0; a < 4; a++) {
        int m = ty * 4 + a;
        if (m0 + m < cnt) {
            int t = tks[m] >> 2;
            float wm = wls[m];
            float* op = out + (size_t)t * NH + n0 + tx * 4;
#pragma unroll
            for (int b = 0; b < 4; b++)
                atomicAdd(op + b, acc[a][b] * wm);
        }
    }
}

extern "C" void kernel_launch(void* const* d_in, const int* in_sizes, int n_in,
                              void* d_out, int out_size, void* d_ws, size_t ws_size,
                              hipStream_t stream) {
    const float* hidden = (const float*)d_in[0];
    const int*   tk_idx = (const int*)d_in[1];
    const float* tk_w   = (const float*)d_in[2];
    const float* gup    = (const float*)d_in[3];
    const float* down   = (const float*)d_in[4];
    float* out = (float*)d_out;

    // workspace layout
    char* ws = (char*)d_ws;
    int*   counts = (int*)ws;                               // 256 B (32 used)
    int*   tok    = (int*)(ws + 256);                       // NE*CAP*4 = 64 KB
    float* wgt    = (float*)(ws + 256 + NE * CAP * 4);      // 64 KB
    float* hbuf   = (float*)(ws + 256 + 2 * NE * CAP * 4);  // NT*NK*NI*4 = 16.8 MB

    hipMemsetAsync(counts, 0, 256, stream);
    hipMemsetAsync(out, 0, (size_t)NT * NH * sizeof(float), stream);

    route_kernel<<<(NT * NK + 255) / 256, 256, 0, stream>>>(tk_idx, tk_w, counts, tok, wgt);

    dim3 gridC(NI / TN, CAP / TM, NE);   // (8, 8, 32)
    gateup_kernel<<<gridC, 256, 0, stream>>>(hidden, gup, counts, tok, hbuf);

    dim3 gridD(NH / TN, CAP / TM, NE);   // (16, 8, 32)
    down_kernel<<<gridD, 256, 0, stream>>>(hbuf, down, counts, tok, wgt, out);
}

// Round 2
// 402.589 us; speedup vs baseline: 1.6822x; 1.6822x over previous
//
#include <hip/hip_runtime.h>

#define NE 32
#define NT 2048
#define NH 1024
#define NI 512
#define NK 4
#define CAP 512

typedef __attribute__((ext_vector_type(8))) short short8;
typedef __attribute__((ext_vector_type(4))) float floatx4;

// ---- fp32 -> bf16 (RNE) pair pack -> one dword ----
static __device__ __forceinline__ unsigned pk_bf16(float x, float y) {
#if __has_builtin(__builtin_amdgcn_cvt_pk_bf16_f32)
    typedef __attribute__((ext_vector_type(2))) __bf16 bf16x2;
    union { bf16x2 v; unsigned u; } c;
    c.v = __builtin_amdgcn_cvt_pk_bf16_f32(x, y);
    return c.u;
#else
    union { float f; unsigned u; } a, b;
    a.f = x; b.f = y;
    unsigned ua = (a.u + 0x7fffu + ((a.u >> 16) & 1u)) >> 16;
    unsigned ub = (b.u + 0x7fffu + ((b.u >> 16) & 1u)) >> 16;
    return (ua & 0xffffu) | (ub << 16);
#endif
}

static __device__ __forceinline__ short8 pack8(const float* p) {
    union { unsigned u[4]; short8 s; } c;
    c.u[0] = pk_bf16(p[0], p[1]);
    c.u[1] = pk_bf16(p[2], p[3]);
    c.u[2] = pk_bf16(p[4], p[5]);
    c.u[3] = pk_bf16(p[6], p[7]);
    return c.s;
}

static __device__ __forceinline__ unsigned short bf16_1(float x) {
    return (unsigned short)(pk_bf16(x, 0.f) & 0xffffu);
}

// ---------------- routing ----------------
__global__ void route_kernel(const int* __restrict__ idx,
                             const float* __restrict__ w,
                             int* __restrict__ counts,
                             int* __restrict__ tok,
                             float* __restrict__ wgt) {
    int tid = blockIdx.x * blockDim.x + threadIdx.x;
    if (tid >= NT * NK) return;
    int e = idx[tid];
    int pos = atomicAdd(&counts[e], 1);
    if (pos < CAP) {
        tok[e * CAP + pos] = tid;          // tid = t*NK + k
        wgt[e * CAP + pos] = w[tid];
    }
}

// ---------------- hidden fp32 -> bf16 ----------------
__global__ void cvt_hidden(const float* __restrict__ hidden,
                           unsigned short* __restrict__ hb16) {
    size_t i = (size_t)(blockIdx.x * 256 + threadIdx.x) * 8;
    float tmp[8];
    *(floatx4*)tmp       = *(const floatx4*)(hidden + i);
    *(floatx4*)(tmp + 4) = *(const floatx4*)(hidden + i + 4);
    *(short8*)(hb16 + i) = pack8(tmp);
}

// ---------------- gate/up MFMA GEMM + SiLU ----------------
// tile: 128 entries x 64 j (gate AND up), BK=64, 4 waves (2 row-halves x {gate,up})
__global__ __launch_bounds__(256) void gateup_mfma(
    const unsigned short* __restrict__ hb16,   // [NT][NH] bf16
    const float* __restrict__ gup,             // [NE][2*NI][NH] fp32
    const int* __restrict__ counts,
    const int* __restrict__ tok,
    unsigned short* __restrict__ hbuf)         // [NT*NK][NI] bf16
{
    int e = blockIdx.z;
    int cnt = counts[e];
    int m0 = blockIdx.y * 128;
    if (m0 >= cnt) return;
    int j0 = blockIdx.x * 64;

    __shared__ __align__(16) char smem[36864];   // As[128][72] bf16 | Bs[128][72] bf16 ; reused as upb[2][64][68] f32
    __shared__ int tks[128];

    short (*As)[72] = (short(*)[72])smem;
    short (*Bs)[72] = (short(*)[72])(smem + 18432);
    float (*upb)[64][68] = (float(*)[64][68])smem;

    int tid = threadIdx.x;
    if (tid < 128) {
        int mi = m0 + tid;
        tks[tid] = tok[e * CAP + (mi < cnt ? mi : m0)];
    }
    __syncthreads();

    // staging assignment: thread -> (row, k-half)
    int srow = tid >> 1;
    int shalf = tid & 1;
    const unsigned short* ag = hb16 + (size_t)(tks[srow] >> 2) * NH + shalf * 32;
    const float* gup_e = gup + (size_t)e * (2 * NI) * NH;
    int gj = (srow < 64) ? (j0 + srow) : (NI + j0 + (srow - 64));
    const float* bg = gup_e + (size_t)gj * NH + shalf * 32;

    int wave = tid >> 6, lane = tid & 63;
    int wm = wave >> 1;          // row half (0/1)
    int wv = wave & 1;           // 0: gate (B rows 0-63), 1: up (B rows 64-127)
    int lcol = lane & 15;
    int quad = lane >> 4;
    int lk = quad * 8;

    floatx4 acc[4][4];
#pragma unroll
    for (int a = 0; a < 4; a++)
#pragma unroll
        for (int b = 0; b < 4; b++) acc[a][b] = (floatx4){0.f, 0.f, 0.f, 0.f};

    for (int h0 = 0; h0 < NH; h0 += 64) {
        // stage A: bf16 copy, 32 elems/thread
#pragma unroll
        for (int q = 0; q < 4; q++)
            *(short8*)&As[srow][shalf * 32 + q * 8] =
                *(const short8*)(ag + h0 + q * 8);
        // stage B: fp32 -> bf16, 32 elems/thread
#pragma unroll
        for (int q = 0; q < 4; q++) {
            float tmp[8];
            *(floatx4*)tmp       = *(const floatx4*)(bg + h0 + q * 8);
            *(floatx4*)(tmp + 4) = *(const floatx4*)(bg + h0 + q * 8 + 4);
            *(short8*)&Bs[srow][shalf * 32 + q * 8] = pack8(tmp);
        }
        __syncthreads();
#pragma unroll
        for (int ks = 0; ks < 2; ks++) {
            short8 af[4], bfr[4];
#pragma unroll
            for (int mt = 0; mt < 4; mt++)
                af[mt] = *(const short8*)&As[wm * 64 + mt * 16 + lcol][ks * 32 + lk];
#pragma unroll
            for (int nt = 0; nt < 4; nt++)
                bfr[nt] = *(const short8*)&Bs[wv * 64 + nt * 16 + lcol][ks * 32 + lk];
#pragma unroll
            for (int mt = 0; mt < 4; mt++)
#pragma unroll
                for (int nt = 0; nt < 4; nt++)
                    acc[mt][nt] = __builtin_amdgcn_mfma_f32_16x16x32_bf16(
                        af[mt], bfr[nt], acc[mt][nt], 0, 0, 0);
        }
        __syncthreads();
    }

    // epilogue: up waves park acc in LDS; gate waves fuse SiLU and store bf16
    if (wv == 1) {
#pragma unroll
        for (int mt = 0; mt < 4; mt++)
#pragma unroll
            for (int nt = 0; nt < 4; nt++)
#pragma unroll
                for (int i = 0; i < 4; i++)
                    upb[wm][mt * 16 + quad * 4 + i][nt * 16 + lcol] = acc[mt][nt][i];
    }
    __syncthreads();
    if (wv == 0) {
#pragma unroll
        for (int mt = 0; mt < 4; mt++) {
#pragma unroll
            for (int i = 0; i < 4; i++) {
                int lm = mt * 16 + quad * 4 + i;   // 0..63 within half
                int m = wm * 64 + lm;
                if (m0 + m < cnt) {
                    unsigned short* hp = hbuf + (size_t)tks[m] * NI + j0;
#pragma unroll
                    for (int nt = 0; nt < 4; nt++) {
                        float g = acc[mt][nt][i];
                        float u = upb[wm][lm][nt * 16 + lcol];
                        float h = g / (1.f + __expf(-g)) * u;
                        hp[nt * 16 + lcol] = bf16_1(h);
                    }
                }
            }
        }
    }
}

// ---------------- down MFMA GEMM + weight-scale + atomic accumulate ----------------
// tile: 128 entries x 128 H-cols, BK=64, waves 2x2
__global__ __launch_bounds__(256) void down_mfma(
    const unsigned short* __restrict__ hbuf,   // [NT*NK][NI] bf16
    const float* __restrict__ down,            // [NE][NH][NI] fp32
    const int* __restrict__ counts,
    const int* __restrict__ tok,
    const float* __restrict__ wgt,
    float* __restrict__ out)                   // [NT][NH] fp32
{
    int e = blockIdx.z;
    int cnt = counts[e];
    int m0 = blockIdx.y * 128;
    if (m0 >= cnt) return;
    int n0 = blockIdx.x * 128;

    __shared__ __align__(16) short As[128][72];
    __shared__ __align__(16) short Bs[128][72];
    __shared__ int tks[128];
    __shared__ float wls[128];

    int tid = threadIdx.x;
    if (tid < 128) {
        int mi = m0 + tid;
        int src = e * CAP + (mi < cnt ? mi : m0);
        tks[tid] = tok[src];
        wls[tid] = wgt[src];
    }
    __syncthreads();

    int srow = tid >> 1;
    int shalf = tid & 1;
    const unsigned short* ag = hbuf + (size_t)tks[srow] * NI + shalf * 32;
    const float* down_e = down + (size_t)e * NH * NI;
    const float* bg = down_e + (size_t)(n0 + srow) * NI + shalf * 32;

    int wave = tid >> 6, lane = tid & 63;
    int wm = wave >> 1, wn = wave & 1;
    int lcol = lane & 15;
    int quad = lane >> 4;
    int lk = quad * 8;

    floatx4 acc[4][4];
#pragma unroll
    for (int a = 0; a < 4; a++)
#pragma unroll
        for (int b = 0; b < 4; b++) acc[a][b] = (floatx4){0.f, 0.f, 0.f, 0.f};

    for (int i0 = 0; i0 < NI; i0 += 64) {
#pragma unroll
        for (int q = 0; q < 4; q++)
            *(short8*)&As[srow][shalf * 32 + q * 8] =
                *(const short8*)(ag + i0 + q * 8);
#pragma unroll
        for (int q = 0; q < 4; q++) {
            float tmp[8];
            *(floatx4*)tmp       = *(const floatx4*)(bg + i0 + q * 8);
            *(floatx4*)(tmp + 4) = *(const floatx4*)(bg + i0 + q * 8 + 4);
            *(short8*)&Bs[srow][shalf * 32 + q * 8] = pack8(tmp);
        }
        __syncthreads();
#pragma unroll
        for (int ks = 0; ks < 2; ks++) {
            short8 af[4], bfr[4];
#pragma unroll
            for (int mt = 0; mt < 4; mt++)
                af[mt] = *(const short8*)&As[wm * 64 + mt * 16 + lcol][ks * 32 + lk];
#pragma unroll
            for (int nt = 0; nt < 4; nt++)
                bfr[nt] = *(const short8*)&Bs[wn * 64 + nt * 16 + lcol][ks * 32 + lk];
#pragma unroll
            for (int mt = 0; mt < 4; mt++)
#pragma unroll
                for (int nt = 0; nt < 4; nt++)
                    acc[mt][nt] = __builtin_amdgcn_mfma_f32_16x16x32_bf16(
                        af[mt], bfr[nt], acc[mt][nt], 0, 0, 0);
        }
        __syncthreads();
    }

#pragma unroll
    for (int mt = 0; mt < 4; mt++)
#pragma unroll
        for (int i = 0; i < 4; i++) {
            int m = wm * 64 + mt * 16 + quad * 4 + i;
            if (m0 + m < cnt) {
                int t = tks[m] >> 2;
                float wl = wls[m];
                float* op = out + (size_t)t * NH + n0 + wn * 64;
#pragma unroll
                for (int nt = 0; nt < 4; nt++)
                    atomicAdd(op + nt * 16 + lcol, acc[mt][nt][i] * wl);
            }
        }
}

extern "C" void kernel_launch(void* const* d_in, const int* in_sizes, int n_in,
                              void* d_out, int out_size, void* d_ws, size_t ws_size,
                              hipStream_t stream) {
    const float* hidden = (const float*)d_in[0];
    const int*   tk_idx = (const int*)d_in[1];
    const float* tk_w   = (const float*)d_in[2];
    const float* gup    = (const float*)d_in[3];
    const float* down   = (const float*)d_in[4];
    float* out = (float*)d_out;

    // workspace layout
    char* ws = (char*)d_ws;
    int*            counts = (int*)ws;                              // 256 B
    int*            tok    = (int*)(ws + 256);                      // 64 KB
    float*          wgt    = (float*)(ws + 256 + NE * CAP * 4);     // 64 KB
    unsigned short* hb16   = (unsigned short*)(ws + 256 + 2 * NE * CAP * 4);          // 4 MB
    unsigned short* hbuf   = (unsigned short*)(ws + 256 + 2 * NE * CAP * 4
                                               + (size_t)NT * NH * 2);                // 8.4 MB

    hipMemsetAsync(counts, 0, 256, stream);
    hipMemsetAsync(out, 0, (size_t)NT * NH * sizeof(float), stream);

    route_kernel<<<(NT * NK + 255) / 256, 256, 0, stream>>>(tk_idx, tk_w, counts, tok, wgt);
    cvt_hidden<<<(NT * NH / 8) / 256, 256, 0, stream>>>(hidden, hb16);

    dim3 gridG(NI / 64, CAP / 128, NE);    // (8, 4, 32)
    gateup_mfma<<<gridG, 256, 0, stream>>>(hb16, gup, counts, tok, hbuf);

    dim3 gridD(NH / 128, CAP / 128, NE);   // (8, 4, 32)
    down_mfma<<<gridD, 256, 0, stream>>>(hbuf, down, counts, tok, wgt, out);
}

// Round 3
// 339.612 us; speedup vs baseline: 1.9942x; 1.1854x over previous
//
#include <hip/hip_runtime.h>

#define NE 32
#define NT 2048
#define NH 1024
#define NI 512
#define NK 4
#define CAP 512

typedef __attribute__((ext_vector_type(8))) short short8;
typedef __attribute__((ext_vector_type(4))) float floatx4;

// ---- fp32 -> bf16 (RNE) pair pack -> one dword ----
static __device__ __forceinline__ unsigned pk_bf16(float x, float y) {
#if __has_builtin(__builtin_amdgcn_cvt_pk_bf16_f32)
    typedef __attribute__((ext_vector_type(2))) __bf16 bf16x2;
    union { bf16x2 v; unsigned u; } c;
    c.v = __builtin_amdgcn_cvt_pk_bf16_f32(x, y);
    return c.u;
#else
    union { float f; unsigned u; } a, b;
    a.f = x; b.f = y;
    unsigned ua = (a.u + 0x7fffu + ((a.u >> 16) & 1u)) >> 16;
    unsigned ub = (b.u + 0x7fffu + ((b.u >> 16) & 1u)) >> 16;
    return (ua & 0xffffu) | (ub << 16);
#endif
}

static __device__ __forceinline__ short8 pack8(const float* p) {
    union { unsigned u[4]; short8 s; } c;
    c.u[0] = pk_bf16(p[0], p[1]);
    c.u[1] = pk_bf16(p[2], p[3]);
    c.u[2] = pk_bf16(p[4], p[5]);
    c.u[3] = pk_bf16(p[6], p[7]);
    return c.s;
}

static __device__ __forceinline__ unsigned short bf16_1(float x) {
    return (unsigned short)(pk_bf16(x, 0.f) & 0xffffu);
}

// ---------------- routing ----------------
__global__ void route_kernel(const int* __restrict__ idx,
                             const float* __restrict__ w,
                             int* __restrict__ counts,
                             int* __restrict__ tok,
                             float* __restrict__ wgt) {
    int tid = blockIdx.x * blockDim.x + threadIdx.x;
    if (tid >= NT * NK) return;
    int e = idx[tid];
    int pos = atomicAdd(&counts[e], 1);
    if (pos < CAP) {
        tok[e * CAP + pos] = tid;          // tid = t*NK + k
        wgt[e * CAP + pos] = w[tid];
    }
}

// ---------------- hidden fp32 -> bf16 ----------------
__global__ void cvt_hidden(const float* __restrict__ hidden,
                           unsigned short* __restrict__ hb16) {
    size_t i = (size_t)(blockIdx.x * 256 + threadIdx.x) * 8;
    float tmp[8];
    *(floatx4*)tmp       = *(const floatx4*)(hidden + i);
    *(floatx4*)(tmp + 4) = *(const floatx4*)(hidden + i + 4);
    *(short8*)(hb16 + i) = pack8(tmp);
}

// ---------------- gate/up MFMA GEMM + SiLU ----------------
// tile: 128 entries x 64 j (gate AND up => 128 B-rows), BK=64
// coalesced staging + register prefetch double-buffer
__global__ __launch_bounds__(256) void gateup_mfma(
    const unsigned short* __restrict__ hb16,   // [NT][NH] bf16
    const float* __restrict__ gup,             // [NE][2*NI][NH] fp32
    const int* __restrict__ counts,
    const int* __restrict__ tok,
    unsigned short* __restrict__ hbuf)         // [NT*NK][NI] bf16
{
    int e = blockIdx.z;
    int cnt = counts[e];
    int m0 = blockIdx.y * 128;
    if (m0 >= cnt) return;
    int j0 = blockIdx.x * 64;

    __shared__ __align__(16) char smem[36864];   // As[128][72] | Bs[128][72] bf16 ; epilogue: upb[2][64][68] f32
    __shared__ int tks[128];

    short (*As)[72] = (short(*)[72])smem;
    short (*Bs)[72] = (short(*)[72])(smem + 18432);
    float (*upb)[64][68] = (float(*)[64][68])smem;

    int tid = threadIdx.x;
    if (tid < 128) {
        int mi = m0 + tid;
        tks[tid] = tok[e * CAP + (mi < cnt ? mi : m0)];
    }
    __syncthreads();

    // ---- coalesced staging assignment ----
    // A: 8 lanes per row (16B each), 32 rows per pass, 4 passes
    int arow_base = tid >> 3;            // 0..31
    int acol = (tid & 7) * 8;            // bf16 col
    const unsigned short* ap[4];
#pragma unroll
    for (int p = 0; p < 4; p++)
        ap[p] = hb16 + (size_t)(tks[p * 32 + arow_base] >> 2) * NH + acol;

    // B: 16 lanes per row (float4 each), 16 rows per pass, 8 passes
    int brow_base = tid >> 4;            // 0..15
    int bcol = (tid & 15) * 4;           // float col
    const float* gup_e = gup + (size_t)e * (2 * NI) * NH;
    const float* bp0 = gup_e + (size_t)(j0 + brow_base) * NH + bcol;
    // pass p global-row offset (floats): gate p<4, up p>=4
#define GUP_OFF(p) ((size_t)(p) * 16 * NH + ((p) >= 4 ? (size_t)(NI - 64) * NH : (size_t)0))

    int wave = tid >> 6, lane = tid & 63;
    int wm = wave >> 1;          // row half
    int wv = wave & 1;           // 0: gate, 1: up
    int lcol = lane & 15;
    int quad = lane >> 4;
    int lk = quad * 8;

    floatx4 acc[4][4];
#pragma unroll
    for (int a = 0; a < 4; a++)
#pragma unroll
        for (int b = 0; b < 4; b++) acc[a][b] = (floatx4){0.f, 0.f, 0.f, 0.f};

    // prefetch tile 0
    short8 ra[4];
    float4 rb[8];
#pragma unroll
    for (int p = 0; p < 4; p++) ra[p] = *(const short8*)(ap[p]);
#pragma unroll
    for (int p = 0; p < 8; p++) rb[p] = *(const float4*)(bp0 + GUP_OFF(p));

    for (int h0 = 0; h0 < NH; h0 += 64) {
        // commit staged regs to LDS
#pragma unroll
        for (int p = 0; p < 4; p++)
            *(short8*)&As[p * 32 + arow_base][acol] = ra[p];
#pragma unroll
        for (int p = 0; p < 8; p++) {
            uint2 u;
            u.x = pk_bf16(rb[p].x, rb[p].y);
            u.y = pk_bf16(rb[p].z, rb[p].w);
            *(uint2*)&Bs[p * 16 + brow_base][bcol] = u;
        }
        __syncthreads();
        // issue next tile's loads inside the MFMA window
        int hn = h0 + 64;
        if (hn < NH) {
#pragma unroll
            for (int p = 0; p < 4; p++) ra[p] = *(const short8*)(ap[p] + hn);
#pragma unroll
            for (int p = 0; p < 8; p++) rb[p] = *(const float4*)(bp0 + GUP_OFF(p) + hn);
        }
        // MFMA on current LDS tile
#pragma unroll
        for (int ks = 0; ks < 2; ks++) {
            short8 af[4], bfr[4];
#pragma unroll
            for (int mt = 0; mt < 4; mt++)
                af[mt] = *(const short8*)&As[wm * 64 + mt * 16 + lcol][ks * 32 + lk];
#pragma unroll
            for (int nt = 0; nt < 4; nt++)
                bfr[nt] = *(const short8*)&Bs[wv * 64 + nt * 16 + lcol][ks * 32 + lk];
#pragma unroll
            for (int mt = 0; mt < 4; mt++)
#pragma unroll
                for (int nt = 0; nt < 4; nt++)
                    acc[mt][nt] = __builtin_amdgcn_mfma_f32_16x16x32_bf16(
                        af[mt], bfr[nt], acc[mt][nt], 0, 0, 0);
        }
        __syncthreads();
    }

    // epilogue: up waves park acc in LDS; gate waves fuse SiLU and store bf16
    if (wv == 1) {
#pragma unroll
        for (int mt = 0; mt < 4; mt++)
#pragma unroll
            for (int nt = 0; nt < 4; nt++)
#pragma unroll
                for (int i = 0; i < 4; i++)
                    upb[wm][mt * 16 + quad * 4 + i][nt * 16 + lcol] = acc[mt][nt][i];
    }
    __syncthreads();
    if (wv == 0) {
#pragma unroll
        for (int mt = 0; mt < 4; mt++) {
#pragma unroll
            for (int i = 0; i < 4; i++) {
                int lm = mt * 16 + quad * 4 + i;
                int m = wm * 64 + lm;
                if (m0 + m < cnt) {
                    unsigned short* hp = hbuf + (size_t)tks[m] * NI + j0;
#pragma unroll
                    for (int nt = 0; nt < 4; nt++) {
                        float g = acc[mt][nt][i];
                        float u = upb[wm][lm][nt * 16 + lcol];
                        float h = g / (1.f + __expf(-g)) * u;
                        hp[nt * 16 + lcol] = bf16_1(h);
                    }
                }
            }
        }
    }
}

// ---------------- down MFMA GEMM + weight-scale + atomic accumulate ----------------
// tile: 128 entries x 128 H-cols, BK=64 over NI (8 iters), waves 2x2
__global__ __launch_bounds__(256) void down_mfma(
    const unsigned short* __restrict__ hbuf,   // [NT*NK][NI] bf16
    const float* __restrict__ down,            // [NE][NH][NI] fp32
    const int* __restrict__ counts,
    const int* __restrict__ tok,
    const float* __restrict__ wgt,
    float* __restrict__ out)                   // [NT][NH] fp32
{
    int e = blockIdx.z;
    int cnt = counts[e];
    int m0 = blockIdx.y * 128;
    if (m0 >= cnt) return;
    int n0 = blockIdx.x * 128;

    __shared__ __align__(16) short As[128][72];
    __shared__ __align__(16) short Bs[128][72];
    __shared__ int tks[128];
    __shared__ float wls[128];

    int tid = threadIdx.x;
    if (tid < 128) {
        int mi = m0 + tid;
        int src = e * CAP + (mi < cnt ? mi : m0);
        tks[tid] = tok[src];
        wls[tid] = wgt[src];
    }
    __syncthreads();

    int arow_base = tid >> 3;
    int acol = (tid & 7) * 8;
    const unsigned short* ap[4];
#pragma unroll
    for (int p = 0; p < 4; p++)
        ap[p] = hbuf + (size_t)tks[p * 32 + arow_base] * NI + acol;

    int brow_base = tid >> 4;
    int bcol = (tid & 15) * 4;
    const float* down_e = down + (size_t)e * NH * NI;
    const float* bp0 = down_e + (size_t)(n0 + brow_base) * NI + bcol;
#define DN_OFF(p) ((size_t)(p) * 16 * NI)

    int wave = tid >> 6, lane = tid & 63;
    int wm = wave >> 1, wn = wave & 1;
    int lcol = lane & 15;
    int quad = lane >> 4;
    int lk = quad * 8;

    floatx4 acc[4][4];
#pragma unroll
    for (int a = 0; a < 4; a++)
#pragma unroll
        for (int b = 0; b < 4; b++) acc[a][b] = (floatx4){0.f, 0.f, 0.f, 0.f};

    short8 ra[4];
    float4 rb[8];
#pragma unroll
    for (int p = 0; p < 4; p++) ra[p] = *(const short8*)(ap[p]);
#pragma unroll
    for (int p = 0; p < 8; p++) rb[p] = *(const float4*)(bp0 + DN_OFF(p));

    for (int i0 = 0; i0 < NI; i0 += 64) {
#pragma unroll
        for (int p = 0; p < 4; p++)
            *(short8*)&As[p * 32 + arow_base][acol] = ra[p];
#pragma unroll
        for (int p = 0; p < 8; p++) {
            uint2 u;
            u.x = pk_bf16(rb[p].x, rb[p].y);
            u.y = pk_bf16(rb[p].z, rb[p].w);
            *(uint2*)&Bs[p * 16 + brow_base][bcol] = u;
        }
        __syncthreads();
        int in = i0 + 64;
        if (in < NI) {
#pragma unroll
            for (int p = 0; p < 4; p++) ra[p] = *(const short8*)(ap[p] + in);
#pragma unroll
            for (int p = 0; p < 8; p++) rb[p] = *(const float4*)(bp0 + DN_OFF(p) + in);
        }
#pragma unroll
        for (int ks = 0; ks < 2; ks++) {
            short8 af[4], bfr[4];
#pragma unroll
            for (int mt = 0; mt < 4; mt++)
                af[mt] = *(const short8*)&As[wm * 64 + mt * 16 + lcol][ks * 32 + lk];
#pragma unroll
            for (int nt = 0; nt < 4; nt++)
                bfr[nt] = *(const short8*)&Bs[wn * 64 + nt * 16 + lcol][ks * 32 + lk];
#pragma unroll
            for (int mt = 0; mt < 4; mt++)
#pragma unroll
                for (int nt = 0; nt < 4; nt++)
                    acc[mt][nt] = __builtin_amdgcn_mfma_f32_16x16x32_bf16(
                        af[mt], bfr[nt], acc[mt][nt], 0, 0, 0);
        }
        __syncthreads();
    }

#pragma unroll
    for (int mt = 0; mt < 4; mt++)
#pragma unroll
        for (int i = 0; i < 4; i++) {
            int m = wm * 64 + mt * 16 + quad * 4 + i;
            if (m0 + m < cnt) {
                int t = tks[m] >> 2;
                float wl = wls[m];
                float* op = out + (size_t)t * NH + n0 + wn * 64;
#pragma unroll
                for (int nt = 0; nt < 4; nt++)
                    atomicAdd(op + nt * 16 + lcol, acc[mt][nt][i] * wl);
            }
        }
}

extern "C" void kernel_launch(void* const* d_in, const int* in_sizes, int n_in,
                              void* d_out, int out_size, void* d_ws, size_t ws_size,
                              hipStream_t stream) {
    const float* hidden = (const float*)d_in[0];
    const int*   tk_idx = (const int*)d_in[1];
    const float* tk_w   = (const float*)d_in[2];
    const float* gup    = (const float*)d_in[3];
    const float* down   = (const float*)d_in[4];
    float* out = (float*)d_out;

    char* ws = (char*)d_ws;
    int*            counts = (int*)ws;                              // 256 B
    int*            tok    = (int*)(ws + 256);                      // 64 KB
    float*          wgt    = (float*)(ws + 256 + NE * CAP * 4);     // 64 KB
    unsigned short* hb16   = (unsigned short*)(ws + 256 + 2 * NE * CAP * 4);          // 4 MB
    unsigned short* hbuf   = (unsigned short*)(ws + 256 + 2 * NE * CAP * 4
                                               + (size_t)NT * NH * 2);                // 8.4 MB

    hipMemsetAsync(counts, 0, 256, stream);
    hipMemsetAsync(out, 0, (size_t)NT * NH * sizeof(float), stream);

    route_kernel<<<(NT * NK + 255) / 256, 256, 0, stream>>>(tk_idx, tk_w, counts, tok, wgt);
    cvt_hidden<<<(NT * NH / 8) / 256, 256, 0, stream>>>(hidden, hb16);

    dim3 gridG(NI / 64, CAP / 128, NE);    // (8, 4, 32)
    gateup_mfma<<<gridG, 256, 0, stream>>>(hb16, gup, counts, tok, hbuf);

    dim3 gridD(NH / 128, CAP / 128, NE);   // (8, 4, 32)
    down_mfma<<<gridD, 256, 0, stream>>>(hbuf, down, counts, tok, wgt, out);
}